// Round 1
// 207.952 us; speedup vs baseline: 1.0216x; 1.0216x over previous
//
#include <hip/hip_runtime.h>

#define BINS 5
#define PTS  2
constexpr int Bx = 2, Cc = 256, Hh = 100, Ww = 152;
constexpr int HW = Hh * Ww;          // 15200
constexpr int NTILE = 238;           // merge pixel tiles (64 px each)
constexpr float EPS_DIV = 1e-6f;
constexpr float GN_EPS  = 1e-5f;

typedef __attribute__((ext_vector_type(8))) _Float16 hfrag;  // 8 fp16 (4 VGPRs)
typedef __attribute__((ext_vector_type(2))) _Float16 h2;     // packed pair
typedef __attribute__((ext_vector_type(4))) float f32x4;     // MFMA C/D

__device__ __forceinline__ ushort f2h(float f) {
    return __builtin_bit_cast(ushort, (_Float16)f);
}
__device__ __forceinline__ float hlo(unsigned u) {
    return (float)__builtin_bit_cast(_Float16, (ushort)(u & 0xffffu));
}
__device__ __forceinline__ float hhi(unsigned u) {
    return (float)__builtin_bit_cast(_Float16, (ushort)(u >> 16));
}

// ---------------------------------------------------------------------------
// K0: convert ef_w, hm1_w, merge_w to fp16 (each 131072 elems)
// ---------------------------------------------------------------------------
__global__ __launch_bounds__(256)
void k_wconv(const float* __restrict__ efw, const float* __restrict__ w1,
             const float* __restrict__ mw, ushort* __restrict__ wb)
{
    int gid = blockIdx.x * 256 + threadIdx.x;
    int e = gid * 4;
    int arr = e >> 17, off = e & 131071;
    const float* src = arr == 0 ? efw : (arr == 1 ? w1 : mw);
    float4 v = *(const float4*)(src + off);
    ushort4 o = { f2h(v.x), f2h(v.y), f2h(v.z), f2h(v.w) };
    *(ushort4*)(wb + e) = o;
}

// ---------------------------------------------------------------------------
// K0b: transpose+convert x[b][c][hw] fp32 -> xbt[b][hw][c] fp16
// ---------------------------------------------------------------------------
__global__ __launch_bounds__(256)
void k_xt(const float* __restrict__ x, ushort* __restrict__ xbt)
{
    __shared__ float tile[32][33];
    const int t = threadIdx.x;
    const int hw0 = blockIdx.x * 32;
    const int c0 = blockIdx.y * 32;
    const int b = blockIdx.z;
    const float* xb = x + ((size_t)b * Cc + c0) * HW + hw0;
    const int tx = t & 31, ty = t >> 5;
    #pragma unroll
    for (int r = 0; r < 4; r++) {
        int c = ty + r * 8;
        tile[c][tx] = xb[(size_t)c * HW + tx];
    }
    __syncthreads();
    const int hwl = t >> 3, c4 = (t & 7) * 4;
    ushort4 o = { f2h(tile[c4 + 0][hwl]), f2h(tile[c4 + 1][hwl]),
                  f2h(tile[c4 + 2][hwl]), f2h(tile[c4 + 3][hwl]) };
    *(ushort4*)&xbt[((size_t)b * HW + hw0 + hwl) * Cc + c0 + c4] = o;
}

// ---------------------------------------------------------------------------
// K1: efp[b][p][pix][c] (fp16) = ef_w @ x + ef_b.
// ---------------------------------------------------------------------------
__global__ __launch_bounds__(256)
void k_ef(const ushort* __restrict__ xbt, const ushort* __restrict__ wbe,
          const float* __restrict__ efb, ushort* __restrict__ efp)
{
    __shared__ ushort As[128 * 72];     // [n][k] pad 72
    __shared__ ushort Bs[64 * 72];      // [pix][k]
    const int t = threadIdx.x;
    const int wv = t >> 6, ln = t & 63;
    const int quad = ln >> 4, l16 = ln & 15;
    const int pix0 = blockIdx.x * 64;
    const int n0 = blockIdx.y * 128;
    const int b = blockIdx.z;
    const ushort* xb = xbt + (size_t)b * HW * Cc;

    f32x4 acc[2][4];
    #pragma unroll
    for (int i = 0; i < 2; i++)
        #pragma unroll
        for (int j = 0; j < 4; j++) acc[i][j] = (f32x4){0.f, 0.f, 0.f, 0.f};

    const int arow = t >> 3, acol = (t & 7) * 8;
    const int srow = t >> 3, scol = (t & 7) * 8;

    for (int k0 = 0; k0 < 256; k0 += 64) {
        #pragma unroll
        for (int r = 0; r < 4; r++) {
            int row = arow + r * 32;
            *(uint4*)&As[row * 72 + acol] =
                *(const uint4*)&wbe[(size_t)(n0 + row) * 256 + k0 + acol];
        }
        #pragma unroll
        for (int r = 0; r < 2; r++) {
            int row = srow + r * 32;
            int pq = pix0 + row; if (pq > HW - 1) pq = HW - 1;
            *(uint4*)&Bs[row * 72 + scol] =
                *(const uint4*)&xb[(size_t)pq * Cc + k0 + scol];
        }
        __syncthreads();
        #pragma unroll
        for (int kk = 0; kk < 64; kk += 32) {
            hfrag af[2], bfr[4];
            #pragma unroll
            for (int dt = 0; dt < 2; dt++)
                af[dt] = *(const hfrag*)&As[(wv * 32 + dt * 16 + l16) * 72 + kk + quad * 8];
            #pragma unroll
            for (int pt = 0; pt < 4; pt++)
                bfr[pt] = *(const hfrag*)&Bs[(pt * 16 + l16) * 72 + kk + quad * 8];
            #pragma unroll
            for (int dt = 0; dt < 2; dt++)
                #pragma unroll
                for (int pt = 0; pt < 4; pt++)
                    acc[dt][pt] = __builtin_amdgcn_mfma_f32_16x16x32_f16(
                        af[dt], bfr[pt], acc[dt][pt], 0, 0, 0);
        }
        __syncthreads();
    }

    float bias[2][4];
    #pragma unroll
    for (int dt = 0; dt < 2; dt++)
        #pragma unroll
        for (int r = 0; r < 4; r++)
            bias[dt][r] = efb[n0 + wv * 32 + dt * 16 + quad * 4 + r];
    #pragma unroll
    for (int dt = 0; dt < 2; dt++)
        #pragma unroll
        for (int pt = 0; pt < 4; pt++) {
            int pix = pt * 16 + l16;
            int ch = wv * 32 + dt * 16 + quad * 4;
            ushort4 o = { f2h(acc[dt][pt][0] + bias[dt][0]),
                          f2h(acc[dt][pt][1] + bias[dt][1]),
                          f2h(acc[dt][pt][2] + bias[dt][2]),
                          f2h(acc[dt][pt][3] + bias[dt][3]) };
            *(ushort4*)&As[pix * 136 + ch] = o;
        }
    __syncthreads();
    const int p = n0 >> 8, cbase = n0 & 255;
    ushort* outb = efp + (size_t)((b * PTS + p) * HW) * Cc;
    #pragma unroll
    for (int r = 0; r < 4; r++) {
        int pix = (t >> 4) + r * 16;
        int ch8 = (t & 15) * 8;
        if (pix0 + pix < HW)
            *(uint4*)&outb[(size_t)(pix0 + pix) * Cc + cbase + ch8] =
                *(const uint4*)&As[pix * 136 + ch8];
    }
}

// ---------------------------------------------------------------------------
// K2: heat[b][p][pix] = exp(sum_d w2[d]*relu(D[d][pix]+b1[d]) + b2)
// ---------------------------------------------------------------------------
__global__ __launch_bounds__(256)
void k_heat(const ushort* __restrict__ efp, const ushort* __restrict__ wb1,
            const float* __restrict__ b1, const float* __restrict__ w2,
            const float* __restrict__ b2, float* __restrict__ heat)
{
    __shared__ ushort As[256 * 72];
    __shared__ ushort Bs[64 * 72];
    __shared__ float red[4][64];
    const int t = threadIdx.x;
    const int wv = t >> 6, ln = t & 63;
    const int quad = ln >> 4, l16 = ln & 15;
    const int pix0 = blockIdx.x * 64;
    const int p = blockIdx.y;
    const int b = blockIdx.z;
    const ushort* efb_ = efp + (size_t)((b * PTS + p) * HW) * Cc;
    const ushort* w1p = wb1 + (size_t)p * Cc * Cc;

    f32x4 acc[4][4];
    #pragma unroll
    for (int i = 0; i < 4; i++)
        #pragma unroll
        for (int j = 0; j < 4; j++) acc[i][j] = (f32x4){0.f, 0.f, 0.f, 0.f};

    const int srow = t >> 3, scol = (t & 7) * 8;

    for (int k0 = 0; k0 < 256; k0 += 64) {
        #pragma unroll
        for (int r = 0; r < 8; r++) {
            int row = srow + r * 32;
            *(uint4*)&As[row * 72 + scol] =
                *(const uint4*)&w1p[(size_t)row * 256 + k0 + scol];
        }
        #pragma unroll
        for (int r = 0; r < 2; r++) {
            int row = srow + r * 32;
            int pq = pix0 + row; if (pq > HW - 1) pq = HW - 1;
            *(uint4*)&Bs[row * 72 + scol] =
                *(const uint4*)&efb_[(size_t)pq * Cc + k0 + scol];
        }
        __syncthreads();
        #pragma unroll
        for (int kk = 0; kk < 64; kk += 32) {
            hfrag af[4], bfr[4];
            #pragma unroll
            for (int dt = 0; dt < 4; dt++)
                af[dt] = *(const hfrag*)&As[(wv * 64 + dt * 16 + l16) * 72 + kk + quad * 8];
            #pragma unroll
            for (int pt = 0; pt < 4; pt++)
                bfr[pt] = *(const hfrag*)&Bs[(pt * 16 + l16) * 72 + kk + quad * 8];
            #pragma unroll
            for (int dt = 0; dt < 4; dt++)
                #pragma unroll
                for (int pt = 0; pt < 4; pt++)
                    acc[dt][pt] = __builtin_amdgcn_mfma_f32_16x16x32_f16(
                        af[dt], bfr[pt], acc[dt][pt], 0, 0, 0);
        }
        __syncthreads();
    }

    const float* b1p = b1 + p * 256;
    const float* w2p = w2 + p * 256;
    float s[4] = {0.f, 0.f, 0.f, 0.f};
    #pragma unroll
    for (int dt = 0; dt < 4; dt++) {
        int chb = wv * 64 + dt * 16 + quad * 4;
        float bb[4], ww[4];
        #pragma unroll
        for (int r = 0; r < 4; r++) { bb[r] = b1p[chb + r]; ww[r] = w2p[chb + r]; }
        #pragma unroll
        for (int pt = 0; pt < 4; pt++)
            #pragma unroll
            for (int r = 0; r < 4; r++) {
                float h = acc[dt][pt][r] + bb[r];
                h = h > 0.f ? h : 0.f;
                s[pt] += ww[r] * h;
            }
    }
    #pragma unroll
    for (int pt = 0; pt < 4; pt++) {
        s[pt] += __shfl_xor(s[pt], 16);
        s[pt] += __shfl_xor(s[pt], 32);
    }
    if (ln < 16) {
        #pragma unroll
        for (int pt = 0; pt < 4; pt++) red[wv][pt * 16 + ln] = s[pt];
    }
    __syncthreads();
    if (t < 64) {
        float v = red[0][t] + red[1][t] + red[2][t] + red[3][t] + b2[p];
        int m = pix0 + t;
        if (m < HW) heat[(size_t)(b * PTS + p) * HW + m] = expf(v);
    }
}

// ---------------------------------------------------------------------------
// K3: deformable sampling.  fp16 packed-FMA inner loop: weights pre-normalized
// and stored as replicated fp16 pairs in phase 1; phase 2 does 4 v_pk_fma_f16
// per uint4 (8 channels) and stores the packed accumulators directly.
// ---------------------------------------------------------------------------
__global__ __launch_bounds__(256)
void k_sample(const ushort* __restrict__ efp, const float* __restrict__ heat,
              const float* __restrict__ offs, ushort* __restrict__ outs)
{
    __shared__ uint2 s_wo[32][20];
    const int t = threadIdx.x;
    const int bid = blockIdx.x;
    const int nx = (bid & 7) * 60 + (bid >> 3);
    if (nx >= 475) return;
    const int m0 = nx * 32;
    const int p = blockIdx.y;
    const int b = blockIdx.z;
    const float* heat_bp = heat + (size_t)(b * PTS + p) * HW;

    if (t < 32 * BINS) {
        int j = t / BINS, k = t % BINS;
        int hw = m0 + j;
        int hh = hw / Ww, ww = hw % Ww;
        int chy = (p * BINS + k) * 2;
        float oy = offs[((size_t)b * (PTS * BINS * 2) + chy)     * HW + hw];
        float ox = offs[((size_t)b * (PTS * BINS * 2) + chy + 1) * HW + hw];
        float ysf = (float)hh + oy;
        float xsf = (float)ww + ox;
        float y0 = floorf(ysf), x0 = floorf(xsf);
        #pragma unroll
        for (int dy = 0; dy < 2; dy++)
            #pragma unroll
            for (int dx = 0; dx < 2; dx++) {
                float yi = y0 + dy, xi = x0 + dx;
                float wgt = (1.f - fabsf(ysf - yi)) * (1.f - fabsf(xsf - xi));
                bool valid = (yi >= 0.f) && (yi <= (float)(Hh - 1)) &&
                             (xi >= 0.f) && (xi <= (float)(Ww - 1));
                int yc = (int)yi; yc = yc < 0 ? 0 : (yc > Hh - 1 ? Hh - 1 : yc);
                int xc = (int)xi; xc = xc < 0 ? 0 : (xc > Ww - 1 ? Ww - 1 : xc);
                int idx = yc * Ww + xc;
                float wh = valid ? wgt * heat_bp[idx] : 0.f;
                s_wo[j][k * 4 + dy * 2 + dx] =
                    make_uint2(__float_as_uint(wh), (unsigned)idx << 9);
            }
    }
    __syncthreads();
    if (t < 32) {
        float s = 0.f;
        #pragma unroll
        for (int u = 0; u < 20; u++) s += __uint_as_float(s_wo[t][u].x);
        float inv = 1.f / (s + EPS_DIV);
        #pragma unroll
        for (int u = 0; u < 20; u++) {
            float w = __uint_as_float(s_wo[t][u].x) * inv;
            unsigned hw16 = (unsigned)f2h(w);
            s_wo[t][u].x = hw16 | (hw16 << 16);   // replicated fp16 pair
        }
    }
    __syncthreads();

    // phase 2: lane-half = pixel, lane&31 = 8-channel group
    const int wv = t >> 6, ln = t & 63;
    const int half = ln >> 5, c8 = ln & 31;
    const char* efbase = (const char*)(efp + (size_t)((b * PTS + p) * HW) * Cc)
                         + c8 * 16;
    ushort* ob = outs + ((size_t)(b * HW + m0)) * (PTS * Cc) + p * Cc + c8 * 8;
    #pragma unroll
    for (int i = 0; i < 8; i += 2) {
        const int j = wv * 8 + i + half;
        h2 a0 = (h2){0, 0}, a1 = (h2){0, 0}, a2 = (h2){0, 0}, a3 = (h2){0, 0};
        #pragma unroll
        for (int u = 0; u < 20; u++) {
            uint2 wo = s_wo[j][u];
            uint4 v = *(const uint4*)(efbase + wo.y);
            h2 wp = __builtin_bit_cast(h2, wo.x);
            a0 += wp * __builtin_bit_cast(h2, v.x);
            a1 += wp * __builtin_bit_cast(h2, v.y);
            a2 += wp * __builtin_bit_cast(h2, v.z);
            a3 += wp * __builtin_bit_cast(h2, v.w);
        }
        uint4 o = { __builtin_bit_cast(unsigned, a0), __builtin_bit_cast(unsigned, a1),
                    __builtin_bit_cast(unsigned, a2), __builtin_bit_cast(unsigned, a3) };
        *(uint4*)(ob + (size_t)j * (PTS * Cc)) = o;
    }
}

// ---------------------------------------------------------------------------
// K4: mgb[b][c][pix] (fp16) = merge_w @ outs + merge_b.  BN=64, no atomics;
// GN partials to part2[b][g][tileX].
// ---------------------------------------------------------------------------
__global__ __launch_bounds__(256)
void k_merge(const ushort* __restrict__ outs, const ushort* __restrict__ wbm,
             const float* __restrict__ mb, ushort* __restrict__ mgb,
             float* __restrict__ part2)
{
    __shared__ ushort As[64 * 72];      // [n][k]
    __shared__ ushort Bs[64 * 72];      // [pix][k]
    const int t = threadIdx.x;
    const int wv = t >> 6, ln = t & 63;
    const int quad = ln >> 4, l16 = ln & 15;
    const int pix0 = blockIdx.x * 64;
    const int n0 = blockIdx.y * 64;
    const int b = blockIdx.z;
    const ushort* ob = outs + (size_t)b * HW * (PTS * Cc);

    f32x4 acc[4];
    #pragma unroll
    for (int j = 0; j < 4; j++) acc[j] = (f32x4){0.f, 0.f, 0.f, 0.f};

    const int srow = t >> 3, scol = (t & 7) * 8;   // srow 0..31

    for (int k0 = 0; k0 < 512; k0 += 64) {
        #pragma unroll
        for (int r = 0; r < 2; r++) {
            int row = srow + r * 32;
            *(uint4*)&As[row * 72 + scol] =
                *(const uint4*)&wbm[(size_t)(n0 + row) * 512 + k0 + scol];
        }
        #pragma unroll
        for (int r = 0; r < 2; r++) {
            int row = srow + r * 32;
            int pq = pix0 + row; if (pq > HW - 1) pq = HW - 1;
            *(uint4*)&Bs[row * 72 + scol] =
                *(const uint4*)&ob[(size_t)pq * (PTS * Cc) + k0 + scol];
        }
        __syncthreads();
        #pragma unroll
        for (int kk = 0; kk < 64; kk += 32) {
            hfrag af = *(const hfrag*)&As[(wv * 16 + l16) * 72 + kk + quad * 8];
            #pragma unroll
            for (int pt = 0; pt < 4; pt++) {
                hfrag bfr = *(const hfrag*)&Bs[(pt * 16 + l16) * 72 + kk + quad * 8];
                acc[pt] = __builtin_amdgcn_mfma_f32_16x16x32_f16(
                    af, bfr, acc[pt], 0, 0, 0);
            }
        }
        __syncthreads();
    }

    const int ch = n0 + wv * 16 + quad * 4;
    float bias[4];
    #pragma unroll
    for (int r = 0; r < 4; r++) bias[r] = mb[ch + r];

    float sacc = 0.f, qacc = 0.f;
    #pragma unroll
    for (int pt = 0; pt < 4; pt++) {
        int pix = pix0 + pt * 16 + l16;
        if (pix < HW) {
            #pragma unroll
            for (int r = 0; r < 4; r++) {
                float v = acc[pt][r] + bias[r];
                mgb[((size_t)b * Cc + ch + r) * HW + pix] = f2h(v);
                sacc += v; qacc += v * v;
            }
        }
    }
    #pragma unroll
    for (int off = 1; off <= 16; off <<= 1) {
        sacc += __shfl_xor(sacc, off);
        qacc += __shfl_xor(qacc, off);
    }
    if ((ln & 31) == 0) {
        int g = (n0 >> 3) + wv * 2 + (quad >> 1);
        size_t idx = ((size_t)(b * 32 + g) * NTILE + blockIdx.x) * 2;
        part2[idx + 0] = sacc;
        part2[idx + 1] = qacc;
    }
}

// ---------------------------------------------------------------------------
// K5: reduce per-tile GN partials -> mean/istd per (b,group).  64 blocks.
// ---------------------------------------------------------------------------
__global__ __launch_bounds__(256)
void k_gnfinal(const float* __restrict__ part2, float* __restrict__ statf)
{
    const int bg = blockIdx.x;           // 0..63
    const int t = threadIdx.x;
    float s = 0.f, q = 0.f;
    if (t < NTILE) {
        s = part2[((size_t)bg * NTILE + t) * 2 + 0];
        q = part2[((size_t)bg * NTILE + t) * 2 + 1];
    }
    #pragma unroll
    for (int off = 1; off <= 32; off <<= 1) {
        s += __shfl_xor(s, off);
        q += __shfl_xor(q, off);
    }
    __shared__ float rs[4], rq[4];
    int wid = t >> 6;
    if ((t & 63) == 0) { rs[wid] = s; rq[wid] = q; }
    __syncthreads();
    if (t == 0) {
        float S = rs[0] + rs[1] + rs[2] + rs[3];
        float Q = rq[0] + rq[1] + rq[2] + rq[3];
        const float n = 8.f * HW;
        float mean = S / n;
        float var  = Q / n - mean * mean;
        statf[bg * 2 + 0] = mean;
        statf[bg * 2 + 1] = rsqrtf(var + GN_EPS);
    }
}

// ---------------------------------------------------------------------------
// K6: apply GN scale/shift + ReLU: read fp16 mgb, write fp32 out
// ---------------------------------------------------------------------------
__global__ __launch_bounds__(256)
void k_gnapply(const ushort* __restrict__ mgb, const float* __restrict__ statf,
               const float* __restrict__ gg, const float* __restrict__ gb,
               float* __restrict__ out)
{
    const int i8 = blockIdx.x * 256 + threadIdx.x;   // 3800 blocks exact
    const int i = i8 * 8;
    const int CHW = Cc * HW;
    const int b = i / CHW;
    const int r = i - b * CHW;
    const int c = r / HW;
    const int g = c >> 3;
    float mean = statf[(b * 32 + g) * 2 + 0];
    float istd = statf[(b * 32 + g) * 2 + 1];
    float sc = istd * gg[c];
    float sh = gb[c] - mean * sc;
    uint4 v = *(const uint4*)(mgb + i);
    float4 o0, o1;
    o0.x = fmaxf(hlo(v.x) * sc + sh, 0.f);
    o0.y = fmaxf(hhi(v.x) * sc + sh, 0.f);
    o0.z = fmaxf(hlo(v.y) * sc + sh, 0.f);
    o0.w = fmaxf(hhi(v.y) * sc + sh, 0.f);
    o1.x = fmaxf(hlo(v.z) * sc + sh, 0.f);
    o1.y = fmaxf(hhi(v.z) * sc + sh, 0.f);
    o1.z = fmaxf(hlo(v.w) * sc + sh, 0.f);
    o1.w = fmaxf(hhi(v.w) * sc + sh, 0.f);
    *(float4*)(out + i)     = o0;
    *(float4*)(out + i + 4) = o1;
}

// ---------------------------------------------------------------------------
extern "C" void kernel_launch(void* const* d_in, const int* in_sizes, int n_in,
                              void* d_out, int out_size, void* d_ws, size_t ws_size,
                              hipStream_t stream)
{
    const float* x    = (const float*)d_in[0];
    const float* offs = (const float*)d_in[1];
    const float* efw  = (const float*)d_in[2];
    const float* efb  = (const float*)d_in[3];
    const float* w1   = (const float*)d_in[4];
    const float* b1   = (const float*)d_in[5];
    const float* w2   = (const float*)d_in[6];
    const float* b2   = (const float*)d_in[7];
    const float* mw   = (const float*)d_in[8];
    const float* mb   = (const float*)d_in[9];
    const float* gg   = (const float*)d_in[10];
    const float* gb   = (const float*)d_in[11];
    float* out = (float*)d_out;

    ushort* wb    = (ushort*)d_ws;
    ushort* wbe   = wb;                          // 131072
    ushort* wb1   = wb + 131072;
    ushort* wbm   = wb + 262144;
    ushort* efp   = wb + 393216;                        // B*P*HW*C fp16
    ushort* outsb = efp + (size_t)Bx * PTS * HW * Cc;   // B*HW*P*C fp16
    ushort* xbt   = outsb + (size_t)Bx * HW * PTS * Cc; // B*HW*C fp16
    ushort* mgb   = xbt + (size_t)Bx * HW * Cc;         // B*C*HW fp16
    float*  heat  = (float*)(mgb + (size_t)Bx * Cc * HW);
    float*  part2 = heat + (size_t)Bx * PTS * HW;       // 64*NTILE*2 floats
    float*  statf = part2 + (size_t)64 * NTILE * 2;     // 128 floats

    dim3 blk(256);
    k_wconv  <<<dim3(384),              blk, 0, stream>>>(efw, w1, mw, wb);
    k_xt     <<<dim3(475, 8, Bx),       blk, 0, stream>>>(x, xbt);
    k_ef     <<<dim3(238, 4, Bx),       blk, 0, stream>>>(xbt, wbe, efb, efp);
    k_heat   <<<dim3(238, PTS, Bx),     blk, 0, stream>>>(efp, wb1, b1, w2, b2, heat);
    k_sample <<<dim3(480, PTS, Bx),     blk, 0, stream>>>(efp, heat, offs, outsb);
    k_merge  <<<dim3(NTILE, 4, Bx),     blk, 0, stream>>>(outsb, wbm, mb, mgb, part2);
    k_gnfinal<<<dim3(64),               blk, 0, stream>>>(part2, statf);
    k_gnapply<<<dim3(Bx * Cc * HW / 8 / 256), blk, 0, stream>>>(mgb, statf, gg, gb, out);
}